// Round 11
// baseline (84.417 us; speedup 1.0000x reference)
//
#include <hip/hip_runtime.h>
#include <math.h>

typedef __attribute__((ext_vector_type(8))) unsigned short ushort8;
typedef __attribute__((ext_vector_type(8))) __bf16 bf16x8;
typedef __attribute__((ext_vector_type(4))) float f32x4;

constexpr int   CDIM  = 256;     // channels
constexpr int   HWSP  = 4096;    // H*W
constexpr int   PPB   = 64;      // positions per tile
constexpr int   TLEN  = 768;     // reversed-w table length (covers base 257..767)
constexpr float SQRTC = 0.031622776601683794f;  // sqrt(0.001)
constexpr float EPSR  = 1e-6f;

__device__ inline unsigned short f2bf(float x) {  // RNE f32 -> bf16
    unsigned int u = __float_as_uint(x);
    u += 0x7FFFu + ((u >> 16) & 1u);
    return (unsigned short)(u >> 16);
}
// bijective on read (pos=m*16+lr) AND write (pos=4*posq+r) patterns:
// measured SQ_LDS_BANK_CONFLICT == 0 in R5/R7/R8 with this exact function.
__device__ inline int swz(int pos) { return ((pos ^ (pos >> 2)) & 15) << 3; }

// ---- builder: w[256] (circular-conv kernel) -> 8 shifted reversed tables:
// Tg[s][i] = bf16( w[(512 - i - s) & 255] ),  s in [0,8), i in [0,TLEN).
// Fragment u[j] = w[(outc-ch0-j)&255] = T[base+j], base = ch0-outc+512;
// copy s = base&7 makes the 16B ds_read_b128 aligned: read Tsh[s][base-s].
__global__ void build_wtab(const float* __restrict__ phi,
                           unsigned short* __restrict__ Tg) {
    __shared__ float w[256];
    const int d = threadIdx.x;
    {
        const float step = 6.283185307179586f / 256.0f;
        double s = 0.0;
        for (int k = 1; k <= 127; ++k) {
            int kd = (k * d) & 255;             // exact mod-2pi reduction
            s += 2.0 * (double)cosf(10.0f * phi[k] + step * (float)kd);
        }
        s += (double)cosf(10.0f * phi[0]);
        double c128 = (double)cosf(10.0f * phi[128]);
        s += (d & 1) ? -c128 : c128;
        w[d] = (float)(s * (1.0 / 256.0));      // irfft drops imag at DC/Nyq
    }
    __syncthreads();
    for (int idx = d; idx < 8 * TLEN; idx += 256) {
        const int s = idx / TLEN, i = idx - s * TLEN;
        Tg[idx] = f2bf(w[(512 - i - s) & 255]);
    }
}

// radial Fourier gate: a0 + sum_{n=1..16} a[n-1]cos(rn) + b[n-1]sin(rn)
__device__ inline float fourier_gate(float r, float A0,
                                     const float* __restrict__ a,
                                     const float* __restrict__ b) {
    float sn, cs;
    sincosf(r, &sn, &cs);
    float c = cs, s = sn, f = A0;
    #pragma unroll
    for (int n = 0; n < 16; ++n) {
        f = fmaf(a[n], c, f);
        f = fmaf(b[n], s, f);
        float c2 = fmaf(c, cs, -s * sn);
        float s2 = fmaf(s, cs,  c * sn);
        c = c2; s = s2;
    }
    return f;
}

__global__ __launch_bounds__(256, 4)
void fused_mfma(const float* __restrict__ x,
                const float* __restrict__ a0_1, const float* __restrict__ a1,
                const float* __restrict__ b1,
                const float* __restrict__ a0_2, const float* __restrict__ a2,
                const float* __restrict__ b2,
                const float* __restrict__ phi,
                const float* __restrict__ alpha, const float* __restrict__ beta,
                const unsigned short* __restrict__ Tg,
                float* __restrict__ out) {
    __shared__ __align__(16) unsigned short Xl[PPB][CDIM];   // 32 KB, swizzled
    __shared__ __align__(16) unsigned short Tsh[8 * TLEN];   // 12 KB W-table
    __shared__ __align__(16) float stats[3][4][PPB];         // nsq / S0 / S_alt
    __shared__ __align__(16) float sobuf[PPB];

    const int t  = threadIdx.x;
    const int l  = t & 63;
    const int g  = t >> 6;
    const int lr = l & 15;
    const int lk = l >> 4;
    const int b  = blockIdx.x >> 6;
    const int s0 = (blockIdx.x & 63) * PPB;
    const float* xb = x + (size_t)b * CDIM * HWSP + s0;

    // ---- stage W-table 12KB global->LDS (replaces 128KB/tile of wpk L1 reads)
    #pragma unroll
    for (int i = 0; i < 3; ++i) {
        const int c8 = t + i * 256;             // 768 ushort8 chunks
        *reinterpret_cast<ushort8*>(&Tsh[c8 * 8]) =
            *reinterpret_cast<const ushort8*>(&Tg[c8 * 8]);
    }

    // ---- stage X: float4 loads (1KB/wave-instr), reg transpose, b128 LDS writes
    // thread = (channel octet co, position quad posq); f32 stats pre-rounding.
    f32x4 vns = {0.f,0.f,0.f,0.f}, vs0 = {0.f,0.f,0.f,0.f}, vsa = {0.f,0.f,0.f,0.f};
    const int posq = t & 15;
    #pragma unroll
    for (int i = 0; i < 2; ++i) {
        const int co = i * 16 + (t >> 4);       // channel octet 0..31
        f32x4 v[8];
        #pragma unroll
        for (int j = 0; j < 8; ++j)
            v[j] = *reinterpret_cast<const f32x4*>(
                       &xb[(size_t)(co * 8 + j) * HWSP + posq * 4]);
        #pragma unroll
        for (int j = 0; j < 8; ++j) {
            vns += v[j] * v[j];
            vs0 += v[j];
            vsa  = (j & 1) ? vsa - v[j] : vsa + v[j];
        }
        #pragma unroll
        for (int r = 0; r < 4; ++r) {           // in-register 8x4 transpose
            ushort8 u;
            #pragma unroll
            for (int j = 0; j < 8; ++j) u[j] = f2bf(v[j][r]);
            const int pos = posq * 4 + r;
            *reinterpret_cast<ushort8*>(&Xl[pos][(co * 8) ^ swz(pos)]) = u;
        }
    }
    // reduce over the 4 lanes sharing posq (l^16, l^32), then lk==0 writes
    #pragma unroll
    for (int r = 0; r < 4; ++r) {
        float aa = vns[r], ss = vs0[r], mm = vsa[r];
        aa += __shfl_xor(aa, 16, 64); aa += __shfl_xor(aa, 32, 64);
        ss += __shfl_xor(ss, 16, 64); ss += __shfl_xor(ss, 32, 64);
        mm += __shfl_xor(mm, 16, 64); mm += __shfl_xor(mm, 32, 64);
        vns[r] = aa; vs0[r] = ss; vsa[r] = mm;
    }
    if (lk == 0) {
        *reinterpret_cast<f32x4*>(&stats[0][g][posq * 4]) = vns;
        *reinterpret_cast<f32x4*>(&stats[1][g][posq * 4]) = vs0;
        *reinterpret_cast<f32x4*>(&stats[2][g][posq * 4]) = vsa;
    }
    __syncthreads();

    // ---- single scalar pass (wave 0), hidden under waves 1-3's MFMA ----
    // Parseval: ||dot||^2 = nsq - [S0^2 sin^2(10*phi0) + Sa^2 sin^2(10*phi128)]/256
    if (t < PPB) {
        float nsq = stats[0][0][t] + stats[0][1][t] + stats[0][2][t] + stats[0][3][t];
        float S0  = stats[1][0][t] + stats[1][1][t] + stats[1][2][t] + stats[1][3][t];
        float Sa  = stats[2][0][t] + stats[2][1][t] + stats[2][2][t] + stats[2][3][t];
        float sin0 = sinf(10.0f * phi[0]);
        float sinN = sinf(10.0f * phi[128]);
        float n0  = sqrtf(nsq);
        float rn0 = fmaxf(n0, EPSR);
        float arg = fminf(SQRTC * rn0, 1.0f - 1e-5f);
        float ls  = atanhf(arg) / (SQRTC * rn0);
        float r1  = fmaxf(ls * n0, EPSR);
        float s1  = ls * fourier_gate(r1, a0_1[0], a1, b1);
        float dn2 = fmaxf(nsq - (S0 * S0 * sin0 * sin0 + Sa * Sa * sinN * sinN)
                                 * (1.0f / 256.0f), 0.f);
        float nv  = sqrtf(dn2) * fabsf(s1);     // ||v0||
        float r2  = fmaxf(nv, EPSR);
        float f2  = fourier_gate(r2, a0_2[0], a2, b2);
        float rn1 = fmaxf(fabsf(f2) * nv, EPSR);
        float es  = tanhf(SQRTC * rn1) / (SQRTC * rn1);
        sobuf[t]  = alpha[0] * es * f2 * s1;    // out = so*dot + beta*h0
    }

    // ---- MFMA: D[pos][outch] = X . Wt ; BOTH operands from LDS now ----
    const int so767 = ((-lr) & 7) * (TLEN - 1);  // addr = base + so*TLEN - so
    f32x4 acc[4][4];
    #pragma unroll
    for (int m = 0; m < 4; ++m)
        #pragma unroll
        for (int n = 0; n < 4; ++n)
            acc[m][n] = f32x4{0.f, 0.f, 0.f, 0.f};

    #pragma unroll
    for (int ks = 0; ks < 8; ++ks) {
        const int kb = ks * 32 + lk * 8;
        bf16x8 af[4], bw[4];
        #pragma unroll
        for (int m = 0; m < 4; ++m) {           // A: X rows (pos), LDS b128
            const int pos = m * 16 + lr;
            af[m] = __builtin_bit_cast(bf16x8,
                *reinterpret_cast<const ushort8*>(&Xl[pos][kb ^ swz(pos)]));
        }
        #pragma unroll
        for (int n = 0; n < 4; ++n) {           // B: circulant frags, LDS b128
            // base = ch0 - outc + 512; aligned addr = base + ((-lr)&7)*767
            const int base = kb + 512 - ((g * 4 + n) * 16 + lr);
            bw[n] = __builtin_bit_cast(bf16x8,
                *reinterpret_cast<const ushort8*>(&Tsh[base + so767]));
        }
        #pragma unroll
        for (int m = 0; m < 4; ++m)
            #pragma unroll
            for (int n = 0; n < 4; ++n)
                acc[m][n] = __builtin_amdgcn_mfma_f32_16x16x32_bf16(
                    af[m], bw[n], acc[m][n], 0, 0, 0);
    }
    __syncthreads();                            // sobuf ready

    // ---- epilogue: reg r = 4 consecutive positions -> dwordx4 stores ----
    const float bb = beta[0];
    float* ob = out + (size_t)b * CDIM * HWSP + s0;
    if (bb == 0.f) {                            // uniform branch
        #pragma unroll
        for (int m = 0; m < 4; ++m) {
            const int p0 = m * 16 + lk * 4;
            const f32x4 sob = *reinterpret_cast<const f32x4*>(&sobuf[p0]);
            #pragma unroll
            for (int n = 0; n < 4; ++n) {
                const int outc = (g * 4 + n) * 16 + lr;
                f32x4 vv = acc[m][n] * sob;
                *reinterpret_cast<f32x4*>(&ob[(size_t)outc * HWSP + p0]) = vv;
            }
        }
    } else {                                    // residual path (x re-read, L2-hot)
        #pragma unroll
        for (int m = 0; m < 4; ++m) {
            const int p0 = m * 16 + lk * 4;
            const f32x4 sob = *reinterpret_cast<const f32x4*>(&sobuf[p0]);
            #pragma unroll
            for (int n = 0; n < 4; ++n) {
                const int outc = (g * 4 + n) * 16 + lr;
                const f32x4 xv = *reinterpret_cast<const f32x4*>(
                                     &xb[(size_t)outc * HWSP + p0]);
                f32x4 vv = acc[m][n] * sob + bb * xv;
                *reinterpret_cast<f32x4*>(&ob[(size_t)outc * HWSP + p0]) = vv;
            }
        }
    }
}

extern "C" void kernel_launch(void* const* d_in, const int* in_sizes, int n_in,
                              void* d_out, int out_size, void* d_ws, size_t ws_size,
                              hipStream_t stream) {
    const float* x     = (const float*)d_in[0];
    const float* a0_1  = (const float*)d_in[1];
    const float* a1    = (const float*)d_in[2];
    const float* b1    = (const float*)d_in[3];
    const float* a0_2  = (const float*)d_in[4];
    const float* a2    = (const float*)d_in[5];
    const float* b2    = (const float*)d_in[6];
    const float* phi   = (const float*)d_in[7];
    const float* alpha = (const float*)d_in[8];
    const float* beta  = (const float*)d_in[9];

    unsigned short* Tg = (unsigned short*)d_ws;             // 12 KB

    build_wtab<<<1, 256, 0, stream>>>(phi, Tg);

    const int B = in_sizes[0] / (CDIM * HWSP);              // 32
    fused_mfma<<<dim3(B * (HWSP / PPB)), dim3(256), 0, stream>>>(
        x, a0_1, a1, b1, a0_2, a2, b2, phi, alpha, beta, Tg, (float*)d_out);
}